// Round 5
// baseline (242.201 us; speedup 1.0000x reference)
//
#include <hip/hip_runtime.h>

typedef unsigned short u16;
typedef __bf16 bf16_t;
typedef bf16_t bf16x8 __attribute__((ext_vector_type(8)));
typedef float f32x4 __attribute__((ext_vector_type(4)));
typedef u16 u16x8 __attribute__((ext_vector_type(8)));
typedef u16 u16x4 __attribute__((ext_vector_type(4)));

#define B_ 8
#define S_ 4096
#define H_ 768
#define M_ (B_ * S_)

// round-to-nearest-even fp32 -> bf16
__device__ __forceinline__ u16 f2b(float f) {
  unsigned u = __float_as_uint(f);
  u += 0x7fffu + ((u >> 16) & 1u);
  return (u16)(u >> 16);
}

// async global->LDS, 16B per lane; lds base must be wave-uniform
__device__ __forceinline__ void gl_lds16(const void* g, void* l) {
  __builtin_amdgcn_global_load_lds(
      (const __attribute__((address_space(1))) void*)g,
      (__attribute__((address_space(3))) void*)l, 16, 0, 0);
}

// ---------------------------------------------------------------------------
// Kernel 1: WbT[n][k] bf16 (n: 0-63=q,64-127=k,128-191=v). Coalesced.
// ---------------------------------------------------------------------------
__global__ __launch_bounds__(256) void wconv_k(const float* __restrict__ Wq,
                                               const float* __restrict__ Wk,
                                               const float* __restrict__ Wv,
                                               u16* __restrict__ WbT) {
  __shared__ float wt[64 * 68];
  const int tid = threadIdx.x;
  int mat = blockIdx.x / 12;
  int k0 = (blockIdx.x % 12) * 64;
  const float* W = (mat == 0) ? Wq : ((mat == 1) ? Wk : Wv);
  int r = tid >> 2, c0 = (tid & 3) * 16;
  const float* src = W + (size_t)(k0 + r) * 64 + c0;
#pragma unroll
  for (int j = 0; j < 16; j += 4)
    *(float4*)&wt[r * 68 + c0 + j] = *(const float4*)(src + j);
  __syncthreads();
  int d = tid >> 2;
  u16* dst = WbT + (size_t)(mat * 64 + d) * 768 + k0 + c0;
  u16x8 o0, o1;
#pragma unroll
  for (int j = 0; j < 8; ++j) o0[j] = f2b(wt[(c0 + j) * 68 + d]);
#pragma unroll
  for (int j = 0; j < 8; ++j) o1[j] = f2b(wt[(c0 + 8 + j) * 68 + d]);
  *(u16x8*)dst = o0;
  *(u16x8*)(dst + 8) = o1;
}

// ---------------------------------------------------------------------------
// Kernel 2: QKV projection. 32-row blocks (1024 blocks = 4 blocks/CU),
// ONE barrier/iter (write goes to the opposite buffer; top barrier orders it),
// dist-2 register prefetch for HBM-resident x.
// q pre-scaled by 0.125*log2(e). q,k stored [s][d]; V stored [b][d][s].
// ---------------------------------------------------------------------------
__global__ __launch_bounds__(256, 4) void qkv_k(const float* __restrict__ x,
                                                const u16* __restrict__ WbT,
                                                const float* __restrict__ bq,
                                                const float* __restrict__ bk,
                                                const float* __restrict__ bv,
                                                u16* __restrict__ qb,
                                                u16* __restrict__ kb,
                                                u16* __restrict__ vbT) {
  // xs[2]: 32x(32+8pad), ws[2]: 192x(32+8pad)
  __shared__ __align__(16) u16 smem[2 * 1280 + 2 * 7680];
  const int tid = threadIdx.x;
  const int w = tid >> 6, ln = tid & 15, qd = (tid >> 4) & 3;
  const int row0 = blockIdx.x * 32;

  const f32x4 z4 = {0.f, 0.f, 0.f, 0.f};
  f32x4 acc[2][3];
#pragma unroll
  for (int rt = 0; rt < 2; ++rt)
#pragma unroll
    for (int ct = 0; ct < 3; ++ct) acc[rt][ct] = z4;

  const int xr = tid >> 3, xc = (tid & 7) * 4;  // x: 32 rows x 32k, 4 f32/thr
  float4 xf;
  u16x8 wf[3];

  auto load_t = [&](int kt) {
    xf = *(const float4*)(x + (size_t)(row0 + xr) * 768 + kt * 32 + xc);
#pragma unroll
    for (int i = 0; i < 3; ++i) {
      int c = i * 256 + tid;
      int r = c >> 2, off = (c & 3) * 8;
      wf[i] = *(const u16x8*)(WbT + (size_t)r * 768 + kt * 32 + off);
    }
  };
  auto write_b = [&](int kt) {
    u16* xs = smem + (kt & 1) * 1280;
    u16* wsb = smem + 2560 + (kt & 1) * 7680;
    u16x4 v;
    v[0] = f2b(xf.x); v[1] = f2b(xf.y); v[2] = f2b(xf.z); v[3] = f2b(xf.w);
    *(u16x4*)&xs[xr * 40 + xc] = v;
#pragma unroll
    for (int i = 0; i < 3; ++i) {
      int c = i * 256 + tid;
      int r = c >> 2, off = (c & 3) * 8;
      *(u16x8*)&wsb[r * 40 + off] = wf[i];
    }
  };

  load_t(0);
  write_b(0);
  load_t(1);
  for (int kt = 0; kt < 24; ++kt) {
    __syncthreads();  // makes buf(kt) visible; orders vs prev readers of buf(kt+1)
    if (kt < 23) {
      write_b(kt + 1);  // opposite buffer — no race with current readers
      if (kt < 22) load_t(kt + 2);
    }
    u16* xs = smem + (kt & 1) * 1280;
    u16* wsb = smem + 2560 + (kt & 1) * 7680;
    bf16x8 af[2], bfr[3];
#pragma unroll
    for (int rt = 0; rt < 2; ++rt)
      af[rt] = *(const bf16x8*)&xs[(rt * 16 + ln) * 40 + qd * 8];
#pragma unroll
    for (int ct = 0; ct < 3; ++ct)
      bfr[ct] = *(const bf16x8*)&wsb[(w * 48 + ct * 16 + ln) * 40 + qd * 8];
#pragma unroll
    for (int rt = 0; rt < 2; ++rt)
#pragma unroll
      for (int ct = 0; ct < 3; ++ct)
        acc[rt][ct] = __builtin_amdgcn_mfma_f32_16x16x32_bf16(
            af[rt], bfr[ct], acc[rt][ct], 0, 0, 0);
  }
  __syncthreads();  // all compute done before LDS reuse below

  u16* vt = smem;  // 64 x 40 u16 reuse for V transpose
#pragma unroll
  for (int ct = 0; ct < 3; ++ct) {
    int col = w * 48 + ct * 16 + ln;
    int mat = col >> 6, d = col & 63;
    if (mat < 2) {
      const float* bp = (mat == 0) ? bq : bk;
      u16* op = (mat == 0) ? qb : kb;
      float bias = bp[d];
      float scale = (mat == 0) ? 0.18033688011112042f : 1.0f;
#pragma unroll
      for (int rt = 0; rt < 2; ++rt)
#pragma unroll
        for (int r = 0; r < 4; ++r)
          op[(size_t)(row0 + rt * 16 + qd * 4 + r) * 64 + d] =
              f2b((acc[rt][ct][r] + bias) * scale);
    } else {
      float bias = bv[d];
#pragma unroll
      for (int rt = 0; rt < 2; ++rt)
#pragma unroll
        for (int r = 0; r < 4; ++r)
          vt[d * 40 + rt * 16 + qd * 4 + r] = f2b(acc[rt][ct][r] + bias);
    }
  }
  __syncthreads();
  {
    int d = tid >> 2, so = (tid & 3) * 8;
    int b = row0 >> 12, s0 = row0 & 4095;
    *(u16x8*)(vbT + ((size_t)b * 64 + d) * 4096 + s0 + so) =
        *(const u16x8*)&vt[d * 40 + so];
  }
}

// ---------------------------------------------------------------------------
// Kernel 3: causal flash attention. Block = 128 q rows (32/wave, qt=2),
// KV chunks of <=8 tiles -> 1152 blocks (4.5/CU grid, 3 resident). Staged K/V
// double-buffered via global_load_lds + XOR swizzle, 1 barrier/iter.
// Swapped operands: S^T = K·Q^T; PV as O^T = V^T·P^T via per-wave LDS
// roundtrip. No running max; bf16 partials combine linearly in comb_k.
// ---------------------------------------------------------------------------
__global__ __launch_bounds__(256, 3) void attn_k(const u16* __restrict__ qb,
                                                 const u16* __restrict__ kb,
                                                 const u16* __restrict__ vbT,
                                                 u16* __restrict__ po,
                                                 float* __restrict__ pl) {
  __shared__ __align__(16) u16 ks[2][4096];      // [t][d] swizzled
  __shared__ __align__(16) u16 vs[2][4096];      // [d][t] swizzled
  __shared__ __align__(16) u16 ps[4 * 16 * 72];  // per-wave P [q][t](+pad)
  const int tid = threadIdx.x;
  const int w = tid >> 6, ln = tid & 15, qd = (tid >> 4) & 3;
  const int id = blockIdx.x;
  const int b = id & 7;
  int t = id >> 3;  // 0..143, qi descending (LPT)
  int qi = 31, rem = t;
  for (;;) {
    int c = (2 * qi + 9) >> 3;  // ceil((2qi+2)/8) chunks for this qi
    if (rem < c) break;
    rem -= c;
    --qi;
  }
  const int chunk = rem;
  const int tstart = rem * 8;
  int tcount = 2 * qi + 2 - tstart;
  if (tcount > 8) tcount = 8;
  const int q0 = qi * 128, q0w = q0 + w * 32;
  const int base = b * S_;
  const u16* kg = kb + (size_t)base * 64;
  const u16* vg = vbT + (size_t)b * 64 * 4096;

  bf16x8 qf[2][2];  // Q^T B-frags == Q A-frags
#pragma unroll
  for (int qt = 0; qt < 2; ++qt) {
    const u16* qrow = qb + (size_t)(base + q0w + qt * 16 + ln) * 64;
    qf[qt][0] = *(const bf16x8*)(qrow + qd * 8);
    qf[qt][1] = *(const bf16x8*)(qrow + 32 + qd * 8);
  }
  const f32x4 z4 = {0.f, 0.f, 0.f, 0.f};
  f32x4 o[2][4];  // O^T C-layout
#pragma unroll
  for (int qt = 0; qt < 2; ++qt)
#pragma unroll
    for (int nt = 0; nt < 4; ++nt) o[qt][nt] = z4;
  float lp[2] = {0.f, 0.f};
  u16* psw = ps + w * (16 * 72);
  const int lr = (tid & 63) >> 3, csl = tid & 7;

  auto prefetch = [&](int bufi, int tile) {
    const u16* kt_ = kg + (size_t)tile * 4096;
    const u16* vt_ = vg + tile * 64;
#pragma unroll
    for (int i = 0; i < 2; ++i) {
      int r0 = w * 16 + i * 8;
      int r = r0 + lr;
      int c = csl ^ (r & 7);
      gl_lds16(kt_ + r * 64 + c * 8, &ks[bufi][r0 * 64]);
      gl_lds16(vt_ + (size_t)r * 4096 + c * 8, &vs[bufi][r0 * 64]);
    }
  };

  prefetch(0, tstart);
  int buf = 0;
  for (int it = 0; it < tcount; ++it) {
    __syncthreads();  // drains prefetch vmcnt; protects buffer reuse
    if (it + 1 < tcount) prefetch(buf ^ 1, tstart + it + 1);
    const int t0a = (tstart + it) * 64;

    // K A-frags and V^T A-frags, register-resident, reused across 2 qt
    bf16x8 kf[2][4], vf[2][4];
#pragma unroll
    for (int kc = 0; kc < 2; ++kc) {
      int cs = ((kc * 4 + qd) ^ (ln & 7)) * 8;
#pragma unroll
      for (int nt = 0; nt < 4; ++nt) {
        kf[kc][nt] = *(const bf16x8*)&ks[buf][(nt * 16 + ln) * 64 + cs];
        vf[kc][nt] = *(const bf16x8*)&vs[buf][(nt * 16 + ln) * 64 + cs];
      }
    }
#pragma unroll
    for (int qt = 0; qt < 2; ++qt) {
      // S^T[t][q]: lane holds col q=..+ln, rows t = t0a + nt*16 + qd*4 + r
      f32x4 s[4] = {z4, z4, z4, z4};
#pragma unroll
      for (int kc = 0; kc < 2; ++kc)
#pragma unroll
        for (int nt = 0; nt < 4; ++nt)
          s[nt] = __builtin_amdgcn_mfma_f32_16x16x32_bf16(kf[kc][nt], qf[qt][kc],
                                                          s[nt], 0, 0, 0);
      if (t0a + 63 > q0w + qt * 16) {  // tile overlaps/past diagonal
#pragma unroll
        for (int nt = 0; nt < 4; ++nt) {
          int tg = t0a + nt * 16 + qd * 4;
          int qg = q0w + qt * 16 + ln;
#pragma unroll
          for (int r = 0; r < 4; ++r)
            if (tg + r > qg) s[nt][r] = -INFINITY;
        }
      }
      // exp2 + packed b64 P-write (pst[q=ln][t])
#pragma unroll
      for (int nt = 0; nt < 4; ++nt) {
        u16x4 pk;
#pragma unroll
        for (int r = 0; r < 4; ++r) {
          float p = __builtin_amdgcn_exp2f(s[nt][r]);
          lp[qt] += p;
          pk[r] = f2b(p);
        }
        *(u16x4*)&psw[ln * 72 + nt * 16 + qd * 4] = pk;
      }
      // O^T += V^T · P^T : P^T B-frag is one b128 per kc
#pragma unroll
      for (int kc = 0; kc < 2; ++kc) {
        bf16x8 pf = *(const bf16x8*)&psw[ln * 72 + kc * 32 + qd * 8];
#pragma unroll
        for (int nt = 0; nt < 4; ++nt)
          o[qt][nt] = __builtin_amdgcn_mfma_f32_16x16x32_bf16(vf[kc][nt], pf,
                                                              o[qt][nt], 0, 0, 0);
      }
    }
    buf ^= 1;
  }

  // epilogue: lp reduce over qd lanes, packed bf16 stores
  u16* poc = po + (size_t)chunk * M_ * 64;
  float* plc = pl + (size_t)chunk * M_;
#pragma unroll
  for (int qt = 0; qt < 2; ++qt) {
    float v = lp[qt];
    v += __shfl_xor(v, 16);
    v += __shfl_xor(v, 32);
    int row = base + q0w + qt * 16 + ln;
#pragma unroll
    for (int nt = 0; nt < 4; ++nt) {
      u16x4 ov;
#pragma unroll
      for (int r = 0; r < 4; ++r) ov[r] = f2b(o[qt][nt][r]);
      *(u16x4*)&poc[(size_t)row * 64 + nt * 16 + qd * 4] = ov;
    }
    if (qd == 0) plc[row] = v;
  }
}

// ---------------------------------------------------------------------------
// Kernel 4: combine <=8 chunk partials: out = sum(o_c) / sum(l_c)
// ---------------------------------------------------------------------------
__global__ __launch_bounds__(256) void comb_k(const u16* __restrict__ po,
                                              const float* __restrict__ pl,
                                              float* __restrict__ out) {
  int idx = blockIdx.x * 256 + threadIdx.x;  // 524288 threads
  int r = idx >> 4, d0 = (idx & 15) * 4;
  int qi = (r & 4095) >> 7;
  int nch = (2 * qi + 9) >> 3;
  float4 a = {0.f, 0.f, 0.f, 0.f};
  float l = 0.f;
  for (int c = 0; c < nch; ++c) {
    u16x4 p = *(const u16x4*)(po + ((size_t)c * M_ + r) * 64 + d0);
    a.x += __uint_as_float((unsigned)p[0] << 16);
    a.y += __uint_as_float((unsigned)p[1] << 16);
    a.z += __uint_as_float((unsigned)p[2] << 16);
    a.w += __uint_as_float((unsigned)p[3] << 16);
    l += pl[(size_t)c * M_ + r];
  }
  float inv = 1.0f / l;
  a.x *= inv; a.y *= inv; a.z *= inv; a.w *= inv;
  *(float4*)(out + (size_t)r * 64 + d0) = a;
}

// ---------------------------------------------------------------------------
extern "C" void kernel_launch(void* const* d_in, const int* in_sizes, int n_in,
                              void* d_out, int out_size, void* d_ws, size_t ws_size,
                              hipStream_t stream) {
  const float* x  = (const float*)d_in[0];
  const float* Wq = (const float*)d_in[1];
  const float* bq = (const float*)d_in[2];
  const float* Wk = (const float*)d_in[3];
  const float* bk = (const float*)d_in[4];
  const float* Wv = (const float*)d_in[5];
  const float* bv = (const float*)d_in[6];
  float* out = (float*)d_out;

  char* wsp = (char*)d_ws;
  u16* WbT  = (u16*)wsp;                     //  294912 B
  u16* qb   = (u16*)(wsp + 294912);          // 4 MiB
  u16* kb   = (u16*)(wsp + 4489216);         // 4 MiB
  u16* vbT  = (u16*)(wsp + 8683520);         // 4 MiB  [b][d][s]
  u16* po   = (u16*)(wsp + 12877824);        // 8 x 4 MiB bf16 chunk partials
  float* pl = (float*)(wsp + 46432256);      // 8 x 128 KiB fp32 l partials

  hipLaunchKernelGGL(wconv_k, dim3(36), dim3(256), 0, stream, Wq, Wk, Wv, WbT);
  hipLaunchKernelGGL(qkv_k, dim3(1024), dim3(256), 0, stream,
                     x, WbT, bq, bk, bv, qb, kb, vbT);
  hipLaunchKernelGGL(attn_k, dim3(1152), dim3(256), 0, stream,
                     qb, kb, vbT, po, pl);
  hipLaunchKernelGGL(comb_k, dim3(2048), dim3(256), 0, stream, po, pl, out);
}